// Round 1
// baseline (145.465 us; speedup 1.0000x reference)
//
#include <hip/hip_runtime.h>
#include <stdint.h>
#include <stddef.h>

#define BATCH 65536
#define OUTF  1024
#define INF   128

typedef float f32x4 __attribute__((ext_vector_type(4)));
typedef __bf16 bf16x8 __attribute__((ext_vector_type(8)));

// RNE float->bf16, packed pair: lo halfword = a, hi halfword = b
__device__ inline uint32_t pack_bf16_rne(float a, float b) {
    uint32_t ua = __builtin_bit_cast(uint32_t, a);
    uint32_t ub = __builtin_bit_cast(uint32_t, b);
    ua += 0x7fffu + ((ua >> 16) & 1u);
    ub += 0x7fffu + ((ub >> 16) & 1u);
    return (ua >> 16) | (ub & 0xffff0000u);
}

// Load 8 contiguous fp32 and convert to a bf16x8 MFMA fragment.
__device__ inline bf16x8 load_frag(const float* __restrict__ p) {
    f32x4 v0 = *(const f32x4*)(p);
    f32x4 v1 = *(const f32x4*)(p + 4);
    union { uint32_t u[4]; bf16x8 b; } f;
    f.u[0] = pack_bf16_rne(v0.x, v0.y);
    f.u[1] = pack_bf16_rne(v0.z, v0.w);
    f.u[2] = pack_bf16_rne(v1.x, v1.y);
    f.u[3] = pack_bf16_rne(v1.z, v1.w);
    return f.b;
}

// One wave per row: sum of squares of 128 fp32 values.
// rows [0, BATCH) -> x rows, rows [BATCH, BATCH+OUTF) -> w rows.
__global__ __launch_bounds__(256) void rowsq_kernel(
        const float* __restrict__ x, const float* __restrict__ w,
        float* __restrict__ ws) {
    int gtid = blockIdx.x * 256 + threadIdx.x;
    int row  = gtid >> 6;
    int lane = threadIdx.x & 63;
    if (row >= BATCH + OUTF) return;
    const float* src = (row < BATCH) ? (x + (size_t)row * INF)
                                     : (w + (size_t)(row - BATCH) * INF);
    float2 v = *(const float2*)(src + lane * 2);
    float s = v.x * v.x + v.y * v.y;
    #pragma unroll
    for (int off = 32; off; off >>= 1) s += __shfl_down(s, off);
    if (lane == 0) ws[row] = s;
}

// 128x128 output tile per block, 4 waves (2x2), mfma 16x16x32 bf16.
__global__ __launch_bounds__(256, 2) void gemm_epi_kernel(
        const float* __restrict__ x, const float* __restrict__ w,
        const float* __restrict__ x2, const float* __restrict__ w2,
        float* __restrict__ out) {
    // bijective XCD-chunked swizzle: nwg = 4096 (divisible by 8)
    int bid = blockIdx.x;
    int swz = (bid & 7) * (4096 / 8) + (bid >> 3);
    int mt = swz >> 3;          // 512 m-tiles
    int nt = swz & 7;           // 8 n-tiles (fast dim -> x panel L2 reuse)
    int m0 = mt * 128, n0 = nt * 128;

    int tid  = threadIdx.x;
    int wid  = tid >> 6;
    int lane = tid & 63;
    int wr = wid >> 1, wc = wid & 1;    // 2x2 wave grid, 64x64 per wave
    int row_base = m0 + wr * 64;
    int col_base = n0 + wc * 64;

    __shared__ float sx2[128];
    __shared__ float sw2[128];
    if (tid < 128) {
        sx2[tid] = x2[m0 + tid];
        sw2[tid] = w2[n0 + tid];
    }
    __syncthreads();

    int l16 = lane & 15;   // row/col within fragment
    int lq  = lane >> 4;   // k-quarter selector

    f32x4 acc[4][4];
    #pragma unroll
    for (int i = 0; i < 4; ++i)
        #pragma unroll
        for (int j = 0; j < 4; ++j)
            acc[i][j] = f32x4{0.f, 0.f, 0.f, 0.f};

    #pragma unroll
    for (int ks = 0; ks < 4; ++ks) {
        int kbase = ks * 32 + lq * 8;
        bf16x8 a[4], b[4];
        #pragma unroll
        for (int im = 0; im < 4; ++im)
            a[im] = load_frag(&x[(size_t)(row_base + im * 16 + l16) * INF + kbase]);
        #pragma unroll
        for (int in = 0; in < 4; ++in)
            b[in] = load_frag(&w[(size_t)(col_base + in * 16 + l16) * INF + kbase]);
        #pragma unroll
        for (int im = 0; im < 4; ++im)
            #pragma unroll
            for (int in = 0; in < 4; ++in)
                acc[im][in] = __builtin_amdgcn_mfma_f32_16x16x32_bf16(
                    a[im], b[in], acc[im][in], 0, 0, 0);
    }

    // Epilogue: out = -0.5 * sqrt(max(x2 + w2 - 2*dot, 0))
    // C/D layout (verified m89/m91): col = lane&15, row = (lane>>4)*4 + reg
    #pragma unroll
    for (int im = 0; im < 4; ++im) {
        #pragma unroll
        for (int in = 0; in < 4; ++in) {
            #pragma unroll
            for (int r = 0; r < 4; ++r) {
                int row = wr * 64 + im * 16 + lq * 4 + r;  // within 128-tile
                int col = wc * 64 + in * 16 + l16;
                float d2 = sx2[row] + sw2[col] - 2.0f * acc[im][in][r];
                d2 = fmaxf(d2, 0.0f);
                out[(size_t)(m0 + row) * OUTF + (n0 + col)] = -0.5f * sqrtf(d2);
            }
        }
    }
}

extern "C" void kernel_launch(void* const* d_in, const int* in_sizes, int n_in,
                              void* d_out, int out_size, void* d_ws, size_t ws_size,
                              hipStream_t stream) {
    const float* x = (const float*)d_in[0];
    const float* w = (const float*)d_in[1];
    float* out = (float*)d_out;
    float* ws  = (float*)d_ws;           // [BATCH] x2 then [OUTF] w2
    float* x2 = ws;
    float* w2 = ws + BATCH;

    rowsq_kernel<<<dim3((BATCH + OUTF) / 4), dim3(256), 0, stream>>>(x, w, ws);
    gemm_epi_kernel<<<dim3(4096), dim3(256), 0, stream>>>(x, w, x2, w2, out);
}

// Round 2
// 99.733 us; speedup vs baseline: 1.4585x; 1.4585x over previous
//
#include <hip/hip_runtime.h>
#include <stdint.h>
#include <stddef.h>

#define BATCH 65536
#define OUTF  1024
#define INF   128

typedef float f32x4 __attribute__((ext_vector_type(4)));
typedef __bf16 bf16x8 __attribute__((ext_vector_type(8)));

// RNE float->bf16, packed pair: lo halfword = a, hi halfword = b
__device__ inline uint32_t pack_bf16_rne(float a, float b) {
    uint32_t ua = __builtin_bit_cast(uint32_t, a);
    uint32_t ub = __builtin_bit_cast(uint32_t, b);
    ua += 0x7fffu + ((ua >> 16) & 1u);
    ub += 0x7fffu + ((ub >> 16) & 1u);
    return (ua >> 16) | (ub & 0xffff0000u);
}

// Prep: one wave per row. Reads fp32 row (128 elems), writes bf16 row
// (64 u32, coalesced 256B) and the row sum-of-squares.
// rows [0, BATCH) -> x, rows [BATCH, BATCH+OUTF) -> w.
__global__ __launch_bounds__(256) void prep_kernel(
        const float* __restrict__ x, const float* __restrict__ w,
        float* __restrict__ sumsq, uint32_t* __restrict__ xb,
        uint32_t* __restrict__ wb) {
    int gtid = blockIdx.x * 256 + threadIdx.x;
    int row  = gtid >> 6;
    int lane = threadIdx.x & 63;
    if (row >= BATCH + OUTF) return;
    const float* src;
    uint32_t* dst;
    if (row < BATCH) {
        src = x + (size_t)row * INF;
        dst = xb + (size_t)row * 64;
    } else {
        src = w + (size_t)(row - BATCH) * INF;
        dst = wb + (size_t)(row - BATCH) * 64;
    }
    float2 v = *(const float2*)(src + lane * 2);
    dst[lane] = pack_bf16_rne(v.x, v.y);
    float s = v.x * v.x + v.y * v.y;
    #pragma unroll
    for (int off = 32; off; off >>= 1) s += __shfl_down(s, off);
    if (lane == 0) sumsq[row] = s;
}

// 128x128 output tile per block, 4 waves (2x2), mfma 16x16x32 bf16.
// A/B fragments loaded directly from pre-converted bf16 (1 dwordx4 each).
__global__ __launch_bounds__(256, 3) void gemm_epi_kernel(
        const __bf16* __restrict__ xb, const __bf16* __restrict__ wb,
        const float* __restrict__ x2, const float* __restrict__ w2,
        float* __restrict__ out) {
    // bijective XCD-chunked swizzle: nwg = 4096 (divisible by 8).
    // Per XCD: nt sweeps fast -> 32KB x-panel L2-resident across 8 n-tiles.
    int bid = blockIdx.x;
    int swz = (bid & 7) * (4096 / 8) + (bid >> 3);
    int mt = swz >> 3;          // 512 m-tiles
    int nt = swz & 7;           // 8 n-tiles
    int m0 = mt * 128, n0 = nt * 128;

    int tid  = threadIdx.x;
    int wid  = tid >> 6;
    int lane = tid & 63;
    int wr = wid >> 1, wc = wid & 1;    // 2x2 wave grid, 64x64 per wave
    int row_base = m0 + wr * 64;
    int col_base = n0 + wc * 64;

    __shared__ float sx2[128];
    __shared__ float sw2[128];
    if (tid < 128) {
        sx2[tid] = x2[m0 + tid];
        sw2[tid] = w2[n0 + tid];
    }
    __syncthreads();

    int l16 = lane & 15;   // row/col within fragment
    int lq  = lane >> 4;   // k-quarter selector

    f32x4 acc[4][4];
    #pragma unroll
    for (int i = 0; i < 4; ++i)
        #pragma unroll
        for (int j = 0; j < 4; ++j)
            acc[i][j] = f32x4{0.f, 0.f, 0.f, 0.f};

    #pragma unroll
    for (int ks = 0; ks < 4; ++ks) {
        int kbase = ks * 32 + lq * 8;
        bf16x8 a[4], b[4];
        #pragma unroll
        for (int im = 0; im < 4; ++im)
            a[im] = *(const bf16x8*)(xb + (size_t)(row_base + im * 16 + l16) * INF + kbase);
        #pragma unroll
        for (int in = 0; in < 4; ++in)
            b[in] = *(const bf16x8*)(wb + (size_t)(col_base + in * 16 + l16) * INF + kbase);
        #pragma unroll
        for (int im = 0; im < 4; ++im)
            #pragma unroll
            for (int in = 0; in < 4; ++in)
                acc[im][in] = __builtin_amdgcn_mfma_f32_16x16x32_bf16(
                    a[im], b[in], acc[im][in], 0, 0, 0);
    }

    // Epilogue: out = -0.5 * sqrt(max(x2 + w2 - 2*dot, 0))
    // C/D layout (verified m89/m91): col = lane&15, row = (lane>>4)*4 + reg
    #pragma unroll
    for (int im = 0; im < 4; ++im) {
        #pragma unroll
        for (int in = 0; in < 4; ++in) {
            #pragma unroll
            for (int r = 0; r < 4; ++r) {
                int row = wr * 64 + im * 16 + lq * 4 + r;  // within 128-tile
                int col = wc * 64 + in * 16 + l16;
                float d2 = sx2[row] + sw2[col] - 2.0f * acc[im][in][r];
                d2 = fmaxf(d2, 0.0f);
                out[(size_t)(m0 + row) * OUTF + (n0 + col)] = -0.5f * sqrtf(d2);
            }
        }
    }
}

extern "C" void kernel_launch(void* const* d_in, const int* in_sizes, int n_in,
                              void* d_out, int out_size, void* d_ws, size_t ws_size,
                              hipStream_t stream) {
    const float* x = (const float*)d_in[0];
    const float* w = (const float*)d_in[1];
    float* out = (float*)d_out;

    // ws layout: [0, 66560*4) f32 sumsq (x2 then w2);
    // xb (bf16 x, 16 MiB) at byte 266240 (256-aligned); wb after it.
    char* ws = (char*)d_ws;
    float* sumsq = (float*)ws;
    float* x2 = sumsq;
    float* w2 = sumsq + BATCH;
    uint32_t* xb_u32 = (uint32_t*)(ws + 266240);
    uint32_t* wb_u32 = (uint32_t*)(ws + 266240 + (size_t)BATCH * INF * 2);
    const __bf16* xb = (const __bf16*)xb_u32;
    const __bf16* wb = (const __bf16*)wb_u32;

    prep_kernel<<<dim3((BATCH + OUTF) / 4), dim3(256), 0, stream>>>(
        x, w, sumsq, xb_u32, wb_u32);
    gemm_epi_kernel<<<dim3(4096), dim3(256), 0, stream>>>(xb, wb, x2, w2, out);
}

// Round 4
// 92.738 us; speedup vs baseline: 1.5685x; 1.0754x over previous
//
#include <hip/hip_runtime.h>
#include <stdint.h>
#include <stddef.h>

#define BATCH 65536
#define OUTF  1024
#define INF   128

typedef float f32x4 __attribute__((ext_vector_type(4)));
typedef __bf16 bf16x8 __attribute__((ext_vector_type(8)));

// RNE float->bf16, packed pair: lo halfword = a, hi halfword = b
__device__ inline uint32_t pack_bf16_rne(float a, float b) {
    uint32_t ua = __builtin_bit_cast(uint32_t, a);
    uint32_t ub = __builtin_bit_cast(uint32_t, b);
    ua += 0x7fffu + ((ua >> 16) & 1u);
    ub += 0x7fffu + ((ub >> 16) & 1u);
    return (ua >> 16) | (ub & 0xffff0000u);
}

// Prep: one wave per row. Reads fp32 row (128 elems), writes bf16 row
// (64 u32, coalesced 256B) and the row sum-of-squares.
// rows [0, BATCH) -> x, rows [BATCH, BATCH+OUTF) -> w.
__global__ __launch_bounds__(256) void prep_kernel(
        const float* __restrict__ x, const float* __restrict__ w,
        float* __restrict__ sumsq, uint32_t* __restrict__ xb,
        uint32_t* __restrict__ wb) {
    int gtid = blockIdx.x * 256 + threadIdx.x;
    int row  = gtid >> 6;
    int lane = threadIdx.x & 63;
    if (row >= BATCH + OUTF) return;
    const float* src;
    uint32_t* dst;
    if (row < BATCH) {
        src = x + (size_t)row * INF;
        dst = xb + (size_t)row * 64;
    } else {
        src = w + (size_t)(row - BATCH) * INF;
        dst = wb + (size_t)(row - BATCH) * 64;
    }
    float2 v = *(const float2*)(src + lane * 2);
    dst[lane] = pack_bf16_rne(v.x, v.y);
    float s = v.x * v.x + v.y * v.y;
    #pragma unroll
    for (int off = 32; off; off >>= 1) s += __shfl_down(s, off);
    if (lane == 0) sumsq[row] = s;
}

#define TPAD 132  // LDS row stride in floats: breaks 4-way write conflict to 2-way (free)

// 128x128 output tile per block, 4 waves (2x2), mfma 16x16x32 bf16.
// Epilogue goes through LDS so global stores are contiguous 512B/row float4.
__global__ __launch_bounds__(256, 2) void gemm_epi_kernel(
        const __bf16* __restrict__ xb, const __bf16* __restrict__ wb,
        const float* __restrict__ x2, const float* __restrict__ w2,
        float* __restrict__ out) {
    // bijective XCD-chunked swizzle: nwg = 4096 (divisible by 8).
    // Per XCD: nt sweeps fast -> 32KB x-panel L2-resident across 8 n-tiles.
    int bid = blockIdx.x;
    int swz = (bid & 7) * (4096 / 8) + (bid >> 3);
    int mt = swz >> 3;          // 512 m-tiles
    int nt = swz & 7;           // 8 n-tiles
    int m0 = mt * 128, n0 = nt * 128;

    int tid  = threadIdx.x;
    int wid  = tid >> 6;
    int lane = tid & 63;
    int wr = wid >> 1, wc = wid & 1;    // 2x2 wave grid, 64x64 per wave
    int row_base = m0 + wr * 64;
    int col_base = n0 + wc * 64;

    __shared__ float sx2[128];
    __shared__ float sw2[128];
    __shared__ float tile[128 * TPAD];
    if (tid < 128) {
        sx2[tid] = x2[m0 + tid];
        sw2[tid] = w2[n0 + tid];
    }
    __syncthreads();

    int l16 = lane & 15;   // row/col within fragment
    int lq  = lane >> 4;   // k-quarter selector

    f32x4 acc[4][4];
    #pragma unroll
    for (int i = 0; i < 4; ++i)
        #pragma unroll
        for (int j = 0; j < 4; ++j)
            acc[i][j] = f32x4{0.f, 0.f, 0.f, 0.f};

    #pragma unroll
    for (int ks = 0; ks < 4; ++ks) {
        int kbase = ks * 32 + lq * 8;
        bf16x8 a[4], b[4];
        #pragma unroll
        for (int im = 0; im < 4; ++im)
            a[im] = *(const bf16x8*)(xb + (size_t)(row_base + im * 16 + l16) * INF + kbase);
        #pragma unroll
        for (int in = 0; in < 4; ++in)
            b[in] = *(const bf16x8*)(wb + (size_t)(col_base + in * 16 + l16) * INF + kbase);
        #pragma unroll
        for (int im = 0; im < 4; ++im)
            #pragma unroll
            for (int in = 0; in < 4; ++in)
                acc[im][in] = __builtin_amdgcn_mfma_f32_16x16x32_bf16(
                    a[im], b[in], acc[im][in], 0, 0, 0);
    }

    // Phase 1: fused epilogue math into LDS tile.
    // C/D layout (verified m89/m91): col = lane&15, row = (lane>>4)*4 + reg
    #pragma unroll
    for (int im = 0; im < 4; ++im) {
        #pragma unroll
        for (int in = 0; in < 4; ++in) {
            #pragma unroll
            for (int r = 0; r < 4; ++r) {
                int row = wr * 64 + im * 16 + lq * 4 + r;  // within 128-tile
                int col = wc * 64 + in * 16 + l16;
                float d2 = sx2[row] + sw2[col] - 2.0f * acc[im][in][r];
                tile[row * TPAD + col] = -0.5f * __builtin_amdgcn_sqrtf(fmaxf(d2, 0.0f));
            }
        }
    }
    __syncthreads();

    // Phase 2: coalesced nontemporal float4 stores, 512B contiguous per row.
    int cg = tid & 31;           // col group (16B)
    int r8 = tid >> 5;           // 0..7
    #pragma unroll
    for (int chunk = 0; chunk < 16; ++chunk) {
        int row = chunk * 8 + r8;
        f32x4 v = *(const f32x4*)&tile[row * TPAD + cg * 4];
        __builtin_nontemporal_store(
            v, (f32x4*)&out[(size_t)(m0 + row) * OUTF + n0 + cg * 4]);
    }
}

extern "C" void kernel_launch(void* const* d_in, const int* in_sizes, int n_in,
                              void* d_out, int out_size, void* d_ws, size_t ws_size,
                              hipStream_t stream) {
    const float* x = (const float*)d_in[0];
    const float* w = (const float*)d_in[1];
    float* out = (float*)d_out;

    // ws layout: [0, 66560*4) f32 sumsq (x2 then w2);
    // xb (bf16 x, 16 MiB) at byte 266240 (256-aligned); wb after it.
    char* ws = (char*)d_ws;
    float* sumsq = (float*)ws;
    float* x2 = sumsq;
    float* w2 = sumsq + BATCH;
    uint32_t* xb_u32 = (uint32_t*)(ws + 266240);
    uint32_t* wb_u32 = (uint32_t*)(ws + 266240 + (size_t)BATCH * INF * 2);
    const __bf16* xb = (const __bf16*)xb_u32;
    const __bf16* wb = (const __bf16*)wb_u32;

    prep_kernel<<<dim3((BATCH + OUTF) / 4), dim3(256), 0, stream>>>(
        x, w, sumsq, xb_u32, wb_u32);
    gemm_epi_kernel<<<dim3(4096), dim3(256), 0, stream>>>(xb, wb, x2, w2, out);
}